// Round 1
// 1381.992 us; speedup vs baseline: 1.7203x; 1.7203x over previous
//
#include <hip/hip_runtime.h>
#include <math.h>

#define D_   64
#define H_   32
#define TPB  256
#define HALF 32      // columns staged per phase
#define PADW 33      // LDS row stride (floats): bank = (tid+k)%32 -> 2 lanes/bank = free

static constexpr float K_SCALE   = 173.71779276130071f;  // 400/ln(10)
static constexpr float K_DEFAULT = 7.6699353278706015f;

__global__ __launch_bounds__(TPB, 4)
void poc_main(const float* __restrict__ x,
              const float* __restrict__ W1,
              const float* __restrict__ b1,
              const float* __restrict__ wr,
              const float* __restrict__ brp,
              const float* __restrict__ wz,
              const float* __restrict__ bzp,
              const int* __restrict__ seg,
              float* __restrict__ denom,
              float* __restrict__ numer,
              int N)
{
    __shared__ float sx[TPB * PADW];   // 33,792 B -> 4 blocks/CU -> 16 waves/CU
    const int tid = threadIdx.x;
    const long long rowBase = (long long)blockIdx.x * TPB;
    const bool fullTile = (rowBase + TPB <= (long long)N);

    // 32 independent accumulator chains -> no FMA-latency stalls
    float h[H_];
    #pragma unroll
    for (int j = 0; j < H_; ++j) h[j] = b1[j];

    const float* xrow = &sx[tid * PADW];

    for (int half = 0; half < 2; ++half) {
        if (half) __syncthreads();     // previous half fully consumed

        // ---- stage 256 rows x 32 cols of x into LDS (coalesced float4) ----
        if (fullTile) {
            const float4* xg = (const float4*)x + rowBase * (D_ / 4) + half * (HALF / 4);
            #pragma unroll
            for (int it = 0; it < 8; ++it) {
                int v = it * TPB + tid;        // float4 slot within half tile
                int r = v >> 3, c = v & 7;     // row 0..255, float4-col 0..7
                float4 val = xg[r * (D_ / 4) + c];
                float* dst = &sx[r * PADW + c * 4];
                dst[0] = val.x; dst[1] = val.y; dst[2] = val.z; dst[3] = val.w;
            }
        } else {  // tail tile (not hit for N=4M; kept for generality)
            #pragma unroll
            for (int it = 0; it < 8; ++it) {
                int v = it * TPB + tid;
                int r = v >> 3, c = v & 7;
                long long row = rowBase + r;
                float4 val = make_float4(0.f, 0.f, 0.f, 0.f);
                if (row < (long long)N)
                    val = ((const float4*)x)[row * (D_ / 4) + half * (HALF / 4) + c];
                float* dst = &sx[r * PADW + c * 4];
                dst[0] = val.x; dst[1] = val.y; dst[2] = val.z; dst[3] = val.w;
            }
        }
        __syncthreads();

        // ---- k-outer MLP accumulation ----
        // W1 row k is 32 CONTIGUOUS floats -> 2x s_load_dwordx16 per step,
        // wave-uniform, scalar-cache resident. FMA: v_fmac with SGPR src.
        const float* wb = W1 + half * HALF * H_;
        #pragma unroll 8
        for (int k = 0; k < HALF; ++k) {
            float xv = xrow[k];                // ds_read, off VALU path
            #pragma unroll
            for (int j = 0; j < H_; ++j)
                h[j] = fmaf(xv, wb[k * H_ + j], h[j]);
        }
    }

    // ---- heads: relu, r, z ----
    float rr = *brp;
    float zz = *bzp;
    #pragma unroll
    for (int j = 0; j < H_; ++j) {
        float hj = fmaxf(h[j], 0.0f);
        rr = fmaf(hj, wr[j], rr);
        zz = fmaf(hj, wz[j], zz);
    }

    // ---- softmax weights: exp(z) directly (numer/denom invariant to
    //      the reference's max-subtraction; |z| small) ----
    long long row = rowBase + tid;
    int sid;
    float ez, ezr;
    if (row < (long long)N) {
        sid = seg[row];
        ez  = __expf(zz);
        ezr = ez * rr;
    } else {
        sid = seg[N - 1];   // zero contribution is safe anywhere
        ez = 0.0f; ezr = 0.0f;
    }

    // ---- per-wave segmented inclusive scan (ids sorted -> few segs/wave) ----
    const int lane = tid & 63;
    #pragma unroll
    for (int off = 1; off < 64; off <<= 1) {
        float au = __shfl_up(ez,  off, 64);
        float bu = __shfl_up(ezr, off, 64);
        int   su = __shfl_up(sid, off, 64);
        if (lane >= off && su == sid) { ez += au; ezr += bu; }
    }
    int sdn = __shfl_down(sid, 1, 64);
    if (lane == 63 || sdn != sid) {       // last lane of each segment run
        atomicAdd(&denom[sid], ez);
        atomicAdd(&numer[sid], ezr);
    }
}

__global__ void poc_final(const float* __restrict__ denom,
                          const float* __restrict__ numer,
                          float* __restrict__ out, int S)
{
    int i = blockIdx.x * blockDim.x + threadIdx.x;
    if (i < S) {
        float d = denom[i];
        // exp(z) > 0 for any contribution, so d == 0 <=> empty segment
        out[i] = (d > 0.0f) ? (K_SCALE * numer[i] / d) : (K_SCALE * K_DEFAULT);
    }
}

extern "C" void kernel_launch(void* const* d_in, const int* in_sizes, int n_in,
                              void* d_out, int out_size, void* d_ws, size_t ws_size,
                              hipStream_t stream)
{
    const float* x   = (const float*)d_in[0];
    const float* W1  = (const float*)d_in[1];
    const float* b1  = (const float*)d_in[2];
    const float* wr  = (const float*)d_in[3];
    const float* br  = (const float*)d_in[4];
    const float* wz  = (const float*)d_in[5];
    const float* bz  = (const float*)d_in[6];
    const int*   seg = (const int*)d_in[7];

    const int N = in_sizes[7];     // 4,194,304 rows
    const int S = out_size;        // 16,384 segments

    float* denom = (float*)d_ws;
    float* numer = denom + S;
    hipMemsetAsync(d_ws, 0, (size_t)2 * S * sizeof(float), stream);

    int nblocks = (N + TPB - 1) / TPB;
    poc_main<<<nblocks, TPB, 0, stream>>>(x, W1, b1, wr, br, wz, bz, seg,
                                          denom, numer, N);
    poc_final<<<(S + 255) / 256, 256, 0, stream>>>(denom, numer, (float*)d_out, S);
}